// Round 12
// baseline (155.752 us; speedup 1.0000x reference)
//
#include <hip/hip_runtime.h>

#define DIM  128
#define HID  32
#define KTOT 384          // 3*DIM
#define TPW  16           // edges per wave-tile

typedef __attribute__((ext_vector_type(4))) float f32x4;
typedef __attribute__((ext_vector_type(2))) float f32x2;
typedef __attribute__((ext_vector_type(8))) int   i32x8;

// fp8 e4m3 (OCP on gfx950) pack via HW converts
static __device__ __forceinline__ unsigned pk4_fp8(float a, float b, float c, float d) {
    unsigned r = __builtin_amdgcn_cvt_pk_fp8_f32(a, b, 0u, false);
    return __builtin_amdgcn_cvt_pk_fp8_f32(c, d, r, true);
}

// elementwise product of two 32-byte fp8 vectors (8 dwords), result fp8
static __device__ __forceinline__ i32x8 prod_fp8x32(i32x8 a, i32x8 b) {
    i32x8 r;
#pragma unroll
    for (int j = 0; j < 8; j++) {
        unsigned av = (unsigned)a[j], bv = (unsigned)b[j];
        f32x2 a0 = __builtin_amdgcn_cvt_pk_f32_fp8(av, false);
        f32x2 a1 = __builtin_amdgcn_cvt_pk_f32_fp8(av, true);
        f32x2 b0 = __builtin_amdgcn_cvt_pk_f32_fp8(bv, false);
        f32x2 b1 = __builtin_amdgcn_cvt_pk_f32_fp8(bv, true);
        f32x2 p0 = a0 * b0, p1 = a1 * b1;
        unsigned pr = __builtin_amdgcn_cvt_pk_fp8_f32(p0.x, p0.y, 0u, false);
        pr = __builtin_amdgcn_cvt_pk_fp8_f32(p1.x, p1.y, pr, true);
        r[j] = (int)pr;
    }
    return r;
}

// 32-byte (8-dword) load as two dwordx4
static __device__ __forceinline__ i32x8 ld32(const unsigned char* p) {
    int4 lo = *(const int4*)p;
    int4 hi = *(const int4*)(p + 16);
    i32x8 v;
    v[0] = lo.x; v[1] = lo.y; v[2] = lo.z; v[3] = lo.w;
    v[4] = hi.x; v[5] = hi.y; v[6] = hi.z; v[7] = hi.w;
    return v;
}

// ---------------------------------------------------------------------------
// Kernel 0: wsum[r] = sum_d W[r][d] + bucket-cursor init (re-done every call:
// ws is re-poisoned each iteration). einsum 'ed,ef->e' factorizes:
// bilinear[e] = (z_src.wsum)*(sum z_dst) = s1[src]*s2[dst].
// ---------------------------------------------------------------------------
__global__ __launch_bounds__(256) void wsum_kernel(const float* __restrict__ W,
                                                   float* __restrict__ wsum,
                                                   int* __restrict__ cursor, int cap)
{
    if (blockIdx.x == 0 && threadIdx.x < 8) cursor[threadIdx.x] = threadIdx.x * cap;
    const int wv = threadIdx.x >> 6, lane = threadIdx.x & 63;
    const int r = blockIdx.x * 4 + wv;            // 0..127
    float2 v = *(const float2*)(W + (size_t)r * DIM + lane * 2);
    float s = v.x + v.y;
    s += __shfl_xor(s, 1);  s += __shfl_xor(s, 2);  s += __shfl_xor(s, 4);
    s += __shfl_xor(s, 8);  s += __shfl_xor(s, 16); s += __shfl_xor(s, 32);
    if (lane == 0) wsum[r] = s;
}

// ---------------------------------------------------------------------------
// Kernel 1 prep:
//  blocks [0,nNodeBlk): half-wave per node -> zb8 = fp8(z), s1 = z.wsum, s2 = sum z
//  blocks [nNodeBlk, +48): w1T8[h][k] = fp8(w1[k][h])  (384x32 transpose)
//  blocks [nNodeBlk+48, +nScatBlk): bucket-scatter of edges by src range —
//   each wave: 256 edges (4/lane), ballot histogram over 8 buckets, ONE
//   wave-aggregated atomicAdd per bucket, write sorted[pos] = (src,dst,orig).
// ---------------------------------------------------------------------------
__global__ __launch_bounds__(256) void prep_kernel(
    const float* __restrict__ z, const float* __restrict__ w1,
    const float* __restrict__ wsum, const int* __restrict__ ei,
    unsigned char* __restrict__ zb8, unsigned char* __restrict__ w1T8,
    float* __restrict__ s1, float* __restrict__ s2,
    int4* __restrict__ sorted, int* __restrict__ cursor,
    int nNodes, int nNodeBlk, int nE, int bucksz)
{
    const int b = blockIdx.x;
    const int tid = threadIdx.x;
    if (b < nNodeBlk) {
        const int n = b * 8 + (tid >> 5);
        const int l32 = tid & 31;
        if (n >= nNodes) return;                   // half-wave-uniform exit

        float4 v = *(const float4*)(z + (size_t)n * DIM + l32 * 4);
        float4 w = *(const float4*)(wsum + l32 * 4);

        float a1 = v.x * w.x + v.y * w.y + v.z * w.z + v.w * w.w;
        float a2 = v.x + v.y + v.z + v.w;

        *(unsigned*)(zb8 + (size_t)n * DIM + l32 * 4) = pk4_fp8(v.x, v.y, v.z, v.w);

        a1 += __shfl_xor(a1, 1);  a1 += __shfl_xor(a1, 2);  a1 += __shfl_xor(a1, 4);
        a1 += __shfl_xor(a1, 8);  a1 += __shfl_xor(a1, 16);
        a2 += __shfl_xor(a2, 1);  a2 += __shfl_xor(a2, 2);  a2 += __shfl_xor(a2, 4);
        a2 += __shfl_xor(a2, 8);  a2 += __shfl_xor(a2, 16);
        if (l32 == 0) { s1[n] = a1; s2[n] = a2; }
    } else if (b < nNodeBlk + 48) {
        const int idx = (b - nNodeBlk) * 256 + tid;    // 0..12287 exact (48 blocks)
        const int k = idx >> 5, h = idx & 31;
        unsigned r = __builtin_amdgcn_cvt_pk_fp8_f32(w1[idx], 0.f, 0u, false);
        w1T8[(size_t)h * KTOT + k] = (unsigned char)(r & 0xff);
    } else {
        const int chunk = (b - nNodeBlk - 48) * 4 + (tid >> 6);
        const int lane = tid & 63;
        const int e0 = chunk * 256 + lane * 4;
        int4 s4 = make_int4(0, 0, 0, 0), d4 = make_int4(0, 0, 0, 0);
        if (e0 + 4 <= nE) {
            s4 = *(const int4*)(ei + e0);
            d4 = *(const int4*)(ei + nE + e0);
        } else if (e0 < nE) {
            int* sp = (int*)&s4; int* dp = (int*)&d4;
            for (int r = 0; r < 4 && e0 + r < nE; r++) { sp[r] = ei[e0 + r]; dp[r] = ei[nE + e0 + r]; }
        }
        const unsigned long long lmlt = (1ull << lane) - 1ull;
        int runBase[8];
#pragma unroll
        for (int q = 0; q < 8; q++) runBase[q] = 0;
        int myB[4], myPos[4];
        const int* sp = (const int*)&s4;
#pragma unroll
        for (int r = 0; r < 4; r++) {
            const bool val = (e0 + r < nE);
            const int bkt = (unsigned)sp[r] / (unsigned)bucksz;
            int myRank = 0;
            myB[r] = bkt; myPos[r] = -1;
#pragma unroll
            for (int q = 0; q < 8; q++) {
                unsigned long long m = __ballot(val && (bkt == q));
                if (val && bkt == q) myRank = __popcll(m & lmlt);
                if (val && bkt == q) myPos[r] = runBase[q] + myRank;
                runBase[q] += __popcll(m);
            }
        }
        int old = 0;
        if (lane < 8) old = atomicAdd(cursor + lane, runBase[lane]);
        const int* dp = (const int*)&d4;
#pragma unroll
        for (int r = 0; r < 4; r++) {
            int bb = __shfl(old, myB[r]);
            if (myPos[r] >= 0)
                sorted[(size_t)bb + myPos[r]] = make_int4(sp[r], dp[r], e0 + r, 0);
        }
    }
}

// ---------------------------------------------------------------------------
// Kernel 2: edge kernel — R9's validated fp8 K=128 MFMA path, with
// src-bucketed edges: bucket b = blockIdx%8 reads src rows only from a 1.6MB
// zb8 slice -> per-XCD L2-resident, halving random L3 traffic. dst stays
// random. out[orig] scatter (4B, L2-absorbed).
// ---------------------------------------------------------------------------
__global__ __launch_bounds__(256, 2) void edge_kernel(
    const unsigned char* __restrict__ zb8, const int4* __restrict__ sorted,
    const int* __restrict__ cursor,
    const float* __restrict__ s1, const float* __restrict__ s2,
    const unsigned char* __restrict__ w1T8, const float* __restrict__ b1,
    const float* __restrict__ w2, const float* __restrict__ b2,
    const float* __restrict__ bias, float* __restrict__ out, int cap)
{
    const int lane = threadIdx.x & 63;
    const int wv   = threadIdx.x >> 6;
    const int l15  = lane & 15;
    const int quad = lane >> 4;
    const int sOne = 0x7F7F7F7F;                  // e8m0 1.0 in every byte

    const int bkt  = blockIdx.x & 7;
    const int base = bkt * cap;
    const int cnt  = cursor[bkt] - base;          // final cursor = base + count
    const int tiles = (cnt + TPW - 1) / TPW;
    const int wpb  = (gridDim.x >> 3) * 4;        // waves per bucket
    int jt = (blockIdx.x >> 3) * 4 + wv;
    if (jt >= tiles) return;

    // B fragments: chunk c covers k=[c*128,(c+1)*128); lane (l15=h-col, quad)
    // holds 32 contiguous k at quad*32. 6 x i32x8 = 48 VGPRs.
    i32x8 B0[3], B1[3];
    {
        const unsigned char* b0p = w1T8 + (size_t)l15 * KTOT + quad * 32;
        const unsigned char* b1p = w1T8 + (size_t)(16 + l15) * KTOT + quad * 32;
#pragma unroll
        for (int c = 0; c < 3; c++) {
            B0[c] = ld32(b0p + c * 128);
            B1[c] = ld32(b1p + c * 128);
        }
    }
    const float b1a = b1[l15],      w2a = w2[l15];
    const float b1b = b1[16 + l15], w2b = w2[16 + l15];
    const float cbias = bias[0] + b2[0];

    for (; jt < tiles; jt += wpb) {
        const int j = jt * TPW + l15;
        int4 E = make_int4(0, 0, -1, 0);
        if (j < cnt) E = sorted[(size_t)base + j];
        const int s_ = E.x, d_ = E.y;
        const float bil = s1[s_] * s2[d_];         // f32 bilinear, replicated/quad

        i32x8 zs8 = ld32(zb8 + (size_t)s_ * DIM + quad * 32);
        i32x8 zd8 = ld32(zb8 + (size_t)d_ * DIM + quad * 32);

        f32x4 acc0 = {0.f, 0.f, 0.f, 0.f};
        f32x4 acc1 = {0.f, 0.f, 0.f, 0.f};
        acc0 = __builtin_amdgcn_mfma_scale_f32_16x16x128_f8f6f4(
                   zs8, B0[0], acc0, 0, 0, 0, sOne, 0, sOne);
        acc1 = __builtin_amdgcn_mfma_scale_f32_16x16x128_f8f6f4(
                   zs8, B1[0], acc1, 0, 0, 0, sOne, 0, sOne);
        acc0 = __builtin_amdgcn_mfma_scale_f32_16x16x128_f8f6f4(
                   zd8, B0[1], acc0, 0, 0, 0, sOne, 0, sOne);
        acc1 = __builtin_amdgcn_mfma_scale_f32_16x16x128_f8f6f4(
                   zd8, B1[1], acc1, 0, 0, 0, sOne, 0, sOne);
        i32x8 p8 = prod_fp8x32(zs8, zd8);
        acc0 = __builtin_amdgcn_mfma_scale_f32_16x16x128_f8f6f4(
                   p8, B0[2], acc0, 0, 0, 0, sOne, 0, sOne);
        acc1 = __builtin_amdgcn_mfma_scale_f32_16x16x128_f8f6f4(
                   p8, B1[2], acc1, 0, 0, 0, sOne, 0, sOne);

        // epilogue (validated R3..R10): C/D col=l15 (h), row=quad*4+r (edge)
#pragma unroll
        for (int r = 0; r < 4; r++) {
            float v = fmaxf(acc0[r] + b1a, 0.f) * w2a
                    + fmaxf(acc1[r] + b1b, 0.f) * w2b;
            v += __shfl_xor(v, 1); v += __shfl_xor(v, 2);
            v += __shfl_xor(v, 4); v += __shfl_xor(v, 8);
            const int eL = quad * 4 + r;
            const float bilr = __shfl(bil, eL);    // bil lives on lanes l15==eL
            const int   oL   = __shfl(E.z, eL);    // orig edge index, same lanes
            if (l15 == r && oL >= 0)
                out[oL] = v + bilr + cbias;
        }
    }
}

// ---------------------------------------------------------------------------
// Workspace: zb8 uchar[nNodes*128] | s1 f32[nNodes] | s2 f32[nNodes]
//          | wsum f32[128] | w1T8 uchar[32*384] | cursor int[8] (32B)
//          | sorted int4[8*cap]                          (~26 MB total)
// R11 BUG FIXED: sorted was at cursor+4 (16B) aliasing cursor[4..7] —
// bucket-0 scatter writes clobbered buckets 4-7's cursors. Now cursor+8.
// ---------------------------------------------------------------------------
extern "C" void kernel_launch(void* const* d_in, const int* in_sizes, int n_in,
                              void* d_out, int out_size, void* d_ws, size_t ws_size,
                              hipStream_t stream)
{
    const float* z    = (const float*)d_in[0];
    const int*   ei   = (const int*)d_in[1];
    const float* W    = (const float*)d_in[2];
    const float* bias = (const float*)d_in[3];
    const float* w1   = (const float*)d_in[4];
    const float* b1   = (const float*)d_in[5];
    const float* w2   = (const float*)d_in[6];
    const float* b2   = (const float*)d_in[7];
    float* out = (float*)d_out;

    const int nNodes = in_sizes[0] / DIM;
    const int nE = out_size;
    const int bucksz = (nNodes + 7) / 8;                       // 12500
    int cap = nE / 8 + nE / 16 + 256;                          // ~1.5x mean
    cap = (cap + 15) & ~15;

    unsigned char* zb8 = (unsigned char*)d_ws;
    float* s1   = (float*)(zb8 + (size_t)nNodes * DIM);
    float* s2   = s1 + nNodes;
    float* wsum = s2 + nNodes;
    unsigned char* w1T8 = (unsigned char*)(wsum + DIM);
    int*  cursor = (int*)(w1T8 + (size_t)HID * KTOT);
    int4* sorted = (int4*)(cursor + 8);                        // past ALL 8 cursors

    wsum_kernel<<<32, 256, 0, stream>>>(W, wsum, cursor, cap);

    const int nNodeBlk = (nNodes + 7) / 8;
    const int nScatBlk = (nE + 1023) / 1024;
    prep_kernel<<<nNodeBlk + 48 + nScatBlk, 256, 0, stream>>>(
        z, w1, wsum, ei, zb8, w1T8, s1, s2, sorted, cursor,
        nNodes, nNodeBlk, nE, bucksz);

    edge_kernel<<<1024, 256, 0, stream>>>(zb8, sorted, cursor, s1, s2, w1T8,
                                          b1, w2, b2, bias, out, cap);
}

// Round 13
// 129.517 us; speedup vs baseline: 1.2026x; 1.2026x over previous
//
#include <hip/hip_runtime.h>

#define DIM  128
#define HID  32
#define KTOT 384          // 3*DIM
#define TPW  16           // edges per wave-tile

typedef __attribute__((ext_vector_type(4))) float f32x4;
typedef __attribute__((ext_vector_type(2))) float f32x2;
typedef __attribute__((ext_vector_type(8))) int   i32x8;

// fp8 e4m3 (OCP on gfx950) pack via HW converts
static __device__ __forceinline__ unsigned pk4_fp8(float a, float b, float c, float d) {
    unsigned r = __builtin_amdgcn_cvt_pk_fp8_f32(a, b, 0u, false);
    return __builtin_amdgcn_cvt_pk_fp8_f32(c, d, r, true);
}

// elementwise product of two 32-byte fp8 vectors (8 dwords), result fp8
static __device__ __forceinline__ i32x8 prod_fp8x32(i32x8 a, i32x8 b) {
    i32x8 r;
#pragma unroll
    for (int j = 0; j < 8; j++) {
        unsigned av = (unsigned)a[j], bv = (unsigned)b[j];
        f32x2 a0 = __builtin_amdgcn_cvt_pk_f32_fp8(av, false);
        f32x2 a1 = __builtin_amdgcn_cvt_pk_f32_fp8(av, true);
        f32x2 b0 = __builtin_amdgcn_cvt_pk_f32_fp8(bv, false);
        f32x2 b1 = __builtin_amdgcn_cvt_pk_f32_fp8(bv, true);
        f32x2 p0 = a0 * b0, p1 = a1 * b1;
        unsigned pr = __builtin_amdgcn_cvt_pk_fp8_f32(p0.x, p0.y, 0u, false);
        pr = __builtin_amdgcn_cvt_pk_fp8_f32(p1.x, p1.y, pr, true);
        r[j] = (int)pr;
    }
    return r;
}

// 32-byte (8-dword) load as two dwordx4
static __device__ __forceinline__ i32x8 ld32(const unsigned char* p) {
    int4 lo = *(const int4*)p;
    int4 hi = *(const int4*)(p + 16);
    i32x8 v;
    v[0] = lo.x; v[1] = lo.y; v[2] = lo.z; v[3] = lo.w;
    v[4] = hi.x; v[5] = hi.y; v[6] = hi.z; v[7] = hi.w;
    return v;
}

// ---------------------------------------------------------------------------
// Kernel 0: wsum[r] = sum_d W[r][d], f32, 32 blocks x 4 rows (wave per row).
// (einsum 'ed,ef->e' factorizes: bilinear[e] = (z_src.wsum)*(sum z_dst))
// ---------------------------------------------------------------------------
__global__ __launch_bounds__(256) void wsum_kernel(const float* __restrict__ W,
                                                   float* __restrict__ wsum)
{
    const int wv = threadIdx.x >> 6, lane = threadIdx.x & 63;
    const int r = blockIdx.x * 4 + wv;            // 0..127
    float2 v = *(const float2*)(W + (size_t)r * DIM + lane * 2);
    float s = v.x + v.y;
    s += __shfl_xor(s, 1);  s += __shfl_xor(s, 2);  s += __shfl_xor(s, 4);
    s += __shfl_xor(s, 8);  s += __shfl_xor(s, 16); s += __shfl_xor(s, 32);
    if (lane == 0) wsum[r] = s;
}

// ---------------------------------------------------------------------------
// Kernel 1 prep: blocks [0,nNodeBlk): half-wave per node —
//   zb8[n][:] = fp8(z[n][:]), s1[n] = z.wsum (f32), s2[n] = sum z (f32)
// blocks [nNodeBlk, +48): w1T8[h][k] = fp8(w1[k][h])  (384x32 transpose)
// ---------------------------------------------------------------------------
__global__ __launch_bounds__(256) void prep_kernel(
    const float* __restrict__ z, const float* __restrict__ w1,
    const float* __restrict__ wsum,
    unsigned char* __restrict__ zb8, unsigned char* __restrict__ w1T8,
    float* __restrict__ s1, float* __restrict__ s2,
    int nNodes, int nNodeBlk)
{
    const int b = blockIdx.x;
    const int tid = threadIdx.x;
    if (b < nNodeBlk) {
        const int n = b * 8 + (tid >> 5);
        const int l32 = tid & 31;
        if (n >= nNodes) return;                   // half-wave-uniform exit

        float4 v = *(const float4*)(z + (size_t)n * DIM + l32 * 4);
        float4 w = *(const float4*)(wsum + l32 * 4);

        float a1 = v.x * w.x + v.y * w.y + v.z * w.z + v.w * w.w;
        float a2 = v.x + v.y + v.z + v.w;

        *(unsigned*)(zb8 + (size_t)n * DIM + l32 * 4) = pk4_fp8(v.x, v.y, v.z, v.w);

        a1 += __shfl_xor(a1, 1);  a1 += __shfl_xor(a1, 2);  a1 += __shfl_xor(a1, 4);
        a1 += __shfl_xor(a1, 8);  a1 += __shfl_xor(a1, 16);
        a2 += __shfl_xor(a2, 1);  a2 += __shfl_xor(a2, 2);  a2 += __shfl_xor(a2, 4);
        a2 += __shfl_xor(a2, 8);  a2 += __shfl_xor(a2, 16);
        if (l32 == 0) { s1[n] = a1; s2[n] = a2; }
    } else {
        const int idx = (b - nNodeBlk) * 256 + tid;    // 0..12287 exact (48 blocks)
        const int k = idx >> 5, h = idx & 31;
        unsigned r = __builtin_amdgcn_cvt_pk_fp8_f32(w1[idx], 0.f, 0u, false);
        w1T8[(size_t)h * KTOT + k] = (unsigned char)(r & 0xff);
    }
}

// ---------------------------------------------------------------------------
// Kernel 2: edge kernel — wave-autonomous, zero LDS/barriers, fp8 gathers,
// K=128 MFMA (mfma_scale_f32_16x16x128_f8f6f4, unit e8m0 scales = fp8 matmul).
// A-frag = 32 contiguous B/lane -> each 128B row fetched by 2 dwordx4 instrs.
// A and B use the same assumed lane->k mapping so the contraction is
// permutation-safe; C/D layout is shape-determined = validated 16x16 epilogue.
// Bilinear in f32 via L2-resident s1/s2. Grid 1024 (R8's 2048 regressed;
// R10's pairing and R12's bucketing both net-regressed — this is the best
// measured configuration: ~35us, bound by random-128B-line service rate).
// ---------------------------------------------------------------------------
__global__ __launch_bounds__(256, 2) void edge_kernel(
    const unsigned char* __restrict__ zb8, const int* __restrict__ ei,
    const float* __restrict__ s1, const float* __restrict__ s2,
    const unsigned char* __restrict__ w1T8, const float* __restrict__ b1,
    const float* __restrict__ w2, const float* __restrict__ b2,
    const float* __restrict__ bias, float* __restrict__ out,
    int nE, int nTiles)
{
    const int lane = threadIdx.x & 63;
    const int wv   = threadIdx.x >> 6;
    const int l15  = lane & 15;
    const int quad = lane >> 4;
    const int sOne = 0x7F7F7F7F;                  // e8m0 1.0 in every byte

    int t = blockIdx.x * 4 + wv;
    const int nW = gridDim.x * 4;
    if (t >= nTiles) return;

    // B fragments: chunk c covers k=[c*128,(c+1)*128); lane (l15=h-col, quad)
    // holds 32 contiguous k at quad*32. 6 x i32x8 = 48 VGPRs.
    i32x8 B0[3], B1[3];
    {
        const unsigned char* b0p = w1T8 + (size_t)l15 * KTOT + quad * 32;
        const unsigned char* b1p = w1T8 + (size_t)(16 + l15) * KTOT + quad * 32;
#pragma unroll
        for (int c = 0; c < 3; c++) {
            B0[c] = ld32(b0p + c * 128);
            B1[c] = ld32(b1p + c * 128);
        }
    }
    const float b1a = b1[l15],      w2a = w2[l15];
    const float b1b = b1[16 + l15], w2b = w2[16 + l15];
    const float cbias = bias[0] + b2[0];

    for (; t < nTiles; t += nW) {
        const int e = t * TPW + l15;
        int s_ = 0, d_ = 0;
        if (e < nE) { s_ = ei[e]; d_ = ei[nE + e]; }
        const float bil = s1[s_] * s2[d_];         // f32 path, lane l15 = edge l15

        // rows: lane (l15=edge, quad) loads 32B at quad*32 -> 2 dwordx4 each
        i32x8 zs8 = ld32(zb8 + (size_t)s_ * DIM + quad * 32);
        i32x8 zd8 = ld32(zb8 + (size_t)d_ * DIM + quad * 32);

        f32x4 acc0 = {0.f, 0.f, 0.f, 0.f};
        f32x4 acc1 = {0.f, 0.f, 0.f, 0.f};
        // chunk 0: zs (K 0..127)
        acc0 = __builtin_amdgcn_mfma_scale_f32_16x16x128_f8f6f4(
                   zs8, B0[0], acc0, 0, 0, 0, sOne, 0, sOne);
        acc1 = __builtin_amdgcn_mfma_scale_f32_16x16x128_f8f6f4(
                   zs8, B1[0], acc1, 0, 0, 0, sOne, 0, sOne);
        // chunk 1: zd (K 128..255)
        acc0 = __builtin_amdgcn_mfma_scale_f32_16x16x128_f8f6f4(
                   zd8, B0[1], acc0, 0, 0, 0, sOne, 0, sOne);
        acc1 = __builtin_amdgcn_mfma_scale_f32_16x16x128_f8f6f4(
                   zd8, B1[1], acc1, 0, 0, 0, sOne, 0, sOne);
        // chunk 2: zs*zd (K 256..383)
        i32x8 p8 = prod_fp8x32(zs8, zd8);
        acc0 = __builtin_amdgcn_mfma_scale_f32_16x16x128_f8f6f4(
                   p8, B0[2], acc0, 0, 0, 0, sOne, 0, sOne);
        acc1 = __builtin_amdgcn_mfma_scale_f32_16x16x128_f8f6f4(
                   p8, B1[2], acc1, 0, 0, 0, sOne, 0, sOne);

        // epilogue (validated R3..R12): C/D col=l15 (h), row=quad*4+r (edge)
        const int e0 = t * TPW;
#pragma unroll
        for (int r = 0; r < 4; r++) {
            float v = fmaxf(acc0[r] + b1a, 0.f) * w2a
                    + fmaxf(acc1[r] + b1b, 0.f) * w2b;
            v += __shfl_xor(v, 1); v += __shfl_xor(v, 2);
            v += __shfl_xor(v, 4); v += __shfl_xor(v, 8);
            const int eL = quad * 4 + r;
            const float bilr = __shfl(bil, eL);    // bil replicated across quads
            if (l15 == r && (e0 + eL) < nE)
                out[e0 + eL] = v + bilr + cbias;
        }
    }
}

// ---------------------------------------------------------------------------
// Workspace: zb8 uchar[nNodes*128] | s1 f32[nNodes] | s2 f32[nNodes]
//          | wsum f32[128] | w1T8 uchar[32*384]        (~13.7 MB)
// ---------------------------------------------------------------------------
extern "C" void kernel_launch(void* const* d_in, const int* in_sizes, int n_in,
                              void* d_out, int out_size, void* d_ws, size_t ws_size,
                              hipStream_t stream)
{
    const float* z    = (const float*)d_in[0];
    const int*   ei   = (const int*)d_in[1];
    const float* W    = (const float*)d_in[2];
    const float* bias = (const float*)d_in[3];
    const float* w1   = (const float*)d_in[4];
    const float* b1   = (const float*)d_in[5];
    const float* w2   = (const float*)d_in[6];
    const float* b2   = (const float*)d_in[7];
    float* out = (float*)d_out;

    const int nNodes = in_sizes[0] / DIM;
    const int nE = out_size;

    unsigned char* zb8 = (unsigned char*)d_ws;
    float* s1   = (float*)(zb8 + (size_t)nNodes * DIM);
    float* s2   = s1 + nNodes;
    float* wsum = s2 + nNodes;
    unsigned char* w1T8 = (unsigned char*)(wsum + DIM);

    wsum_kernel<<<32, 256, 0, stream>>>(W, wsum);

    const int nNodeBlk = (nNodes + 7) / 8;
    prep_kernel<<<nNodeBlk + 48, 256, 0, stream>>>(z, w1, wsum, zb8, w1T8,
                                                   s1, s2, nNodes, nNodeBlk);

    const int nTiles = (nE + TPW - 1) / TPW;
    int grid = 1024;                     // best measured (R8 2048 / R10 pairing regressed)
    if (grid * 4 > nTiles) grid = (nTiles + 3) / 4;
    edge_kernel<<<grid, 256, 0, stream>>>(zb8, ei, s1, s2, w1T8,
                                          b1, w2, b2, bias, out, nE, nTiles);
}